// Round 1
// 197.346 us; speedup vs baseline: 1.1481x; 1.1481x over previous
//
#include <hip/hip_runtime.h>
#include <cstdint>
#include <cstddef>

// KAN layer: out[b,j] = sum_{i,k} basis_k(tanh x[b,i]) * C[j,i,k]
// basis is 2-sparse (adjacent slots lo, lo+1); pad to 16 slots/i.
// R12: A-panel EXPANDED IN LDS. R11's per-MFMA register gather (64-bit
// shift + cndmask chains, ~160 VALU/wave-iter, VALUBusy 53% vs MfmaUtil 18%)
// replaced by: expand() scatters (w0,w1) into a zeroed 32-B 16-slot f16 row
// (2x ds_write_b128 zero + 2x ds_write_b32), fragment load = 1x ds_read_b128.
// A-panel [i][row][32B]: frag-read bank pattern is exactly 8/bank (minimum);
// zero-writes are a free 2-way. KSPL2 8->4: grid 512 = 2 blocks/CU at 64 KB
// LDS, atomic epilogue traffic halved, NIT 32->64.

typedef _Float16 half2_v __attribute__((ext_vector_type(2)));
typedef __fp16  fp16x2  __attribute__((ext_vector_type(2)));
typedef _Float16 f16x8 __attribute__((ext_vector_type(8)));
typedef float f32x4 __attribute__((ext_vector_type(4)));

__device__ __forceinline__ half2_v u32_as_h2(uint32_t u) {
  union { uint32_t u; half2_v h; } c; c.u = u; return c.h;
}
__device__ __forceinline__ uint32_t h2_as_u32(half2_v h) {
  union { uint32_t u; half2_v h; } c; c.h = h; return c.u;
}
__device__ __forceinline__ half2_v cvt_pk_h2(float a, float b) {
  union { fp16x2 f; half2_v h; } c;
  c.f = __builtin_amdgcn_cvt_pkrtz(a, b);
  return c.h;
}
__device__ __forceinline__ float dot2f(half2_v a, half2_v b, float c) {
#if __has_builtin(__builtin_amdgcn_fdot2)
  return __builtin_amdgcn_fdot2(a, b, c, false);
#else
  return c + (float)a[0] * (float)b[0] + (float)a[1] * (float)b[1];
#endif
}
__device__ __forceinline__ uint16_t f16_bits(float v) {
  union { _Float16 h; uint16_t u; } c; c.h = (_Float16)v; return c.u;
}

__device__ __forceinline__ float fast_tanhf(float v) {
  const float e = __expf(2.0f * v);
  return 1.0f - 2.0f / (e + 1.0f);
}

// ---- basis-weight computation (analytic uniform knots; verified R10) ----
#define KSTEP 0.13333333333333333f
#define KINV  7.49999943750004f      // 1/(2/15 + 1e-8)
__device__ __forceinline__ void kan_weights(float xin, float& w0, float& w1, int& lo) {
  float xc = fast_tanhf(xin);
  xc = fminf(fmaxf(xc, -1.0f), 1.0f);
  int m = (int)((xc + 1.0f) * 7.5f);   // interval index; basis continuity makes +-1 ULP safe
  m = min(max(m, 0), 14);
  const float k0 = fmaf((float)m, KSTEP, -1.0f);
  const float up = (xc - k0) * KINV;
  const float dn = (k0 + KSTEP - xc) * KINV;
  // m==0: up on slot 0 | 1<=m<=11: dn on m-1, up on m | m==12: dn on 11 | m>=13: zero
  w0 = (m == 0) ? up : ((m <= 12) ? dn : 0.0f);
  w1 = (m >= 1 && m <= 11) ? up : 0.0f;
  lo = min(max(m - 1, 0), 11);
}

__device__ __forceinline__ void load_lds16(const void* g, void* l) {
  __builtin_amdgcn_global_load_lds((const __attribute__((address_space(1))) void*)g,
                                   (__attribute__((address_space(3))) void*)l, 16, 0, 0);
}

// ================= fast path =================
#define GMM 8192
#define GNN 256
#define KI  16                 // padded slots per i
#define GK2 (1024 * KI)        // 16384
#define KSPL2 4
#define IPER (1024 / KSPL2)    // 256 i per split
#define BM2 128
#define BN2 128
#define NIT (IPER / 4)         // 64 pipeline iters (4 i each)

// prep_B2: f16 B2[j][i*16+s], s=0..11 from coef, 12..15 zero (slot12 unused).
__global__ __launch_bounds__(256)
void kan_prep_B2(const float* __restrict__ coef, uint32_t* __restrict__ B2) {
  const int tid = blockIdx.x * 256 + threadIdx.x;   // flat (j,i), 262144
  const float* cp = coef + (size_t)tid * 13;
  uint32_t w[8];
#pragma unroll
  for (int q = 0; q < 6; ++q) w[q] = h2_as_u32(cvt_pk_h2(cp[2 * q], cp[2 * q + 1]));
  w[6] = 0u; w[7] = 0u;
  uint4* p = (uint4*)(B2 + (size_t)tid * 8);
  p[0] = make_uint4(w[0], w[1], w[2], w[3]);
  p[1] = make_uint4(w[4], w[5], w[6], w[7]);
}

__global__ __launch_bounds__(256)
void kan_gemm6(const float* __restrict__ x, const _Float16* __restrict__ B2,
               float* __restrict__ out) {
  // Bs: double-buffered 2x16 KB (XOR-swizzled, swizzle on the global side since
  // global_load_lds LDS addr = uniform base + lane*16).
  // As: double-buffered 2x16 KB expanded A-panel [4 i][128 rows][16 f16 slots].
  __shared__ __align__(16) char Bs[2][BN2 * 128];
  __shared__ __align__(16) char As[2][4 * 128 * 32];

  const int t    = threadIdx.x;
  const int lane = t & 63;
  const int wv   = t >> 6;
  const int mw   = wv & 1;          // m-half of block (64)
  const int nw   = wv >> 1;         // n-half of block (64)
  const int fr   = lane & 15;
  const int fq   = lane >> 4;
  const int m0   = blockIdx.x * BM2;
  const int n0   = blockIdx.y * BN2;
  const int i00  = blockIdx.z * IPER;

  f32x4 acc[4][4];
#pragma unroll
  for (int a = 0; a < 4; ++a)
#pragma unroll
    for (int b = 0; b < 4; ++b) acc[a][b] = (f32x4){0.f, 0.f, 0.f, 0.f};

  // B staging: 1024 16-B chunks (4/thread), XOR swizzle applied on global side.
  const int sn[4] = { (0 * 256 + t) >> 3, (1 * 256 + t) >> 3,
                      (2 * 256 + t) >> 3, (3 * 256 + t) >> 3 };
  const int sc = t & 7;
  // A-panel production: thread t -> row p_row, i-pair {p_ip, p_ip+1} of the 4-i window.
  const int p_row = t & 127;
  const int p_ip  = (t >> 7) * 2;   // 0 or 2
  const float* xrow = x + (size_t)(m0 + p_row) * 1024 + p_ip;

  auto stageB = [&](int it) {
    const _Float16* Bb = B2 + (size_t)(i00 + it * 4) * KI;
    char* Bd = (char*)Bs[it & 1];
#pragma unroll
    for (int s = 0; s < 4; ++s) {
      const int c = sc ^ (sn[s] & 7);
      load_lds16(Bb + (size_t)(n0 + sn[s]) * GK2 + c * 8, Bd + (s * 256 + t) * 16);
    }
  };
  auto loadx = [&](int it) -> float2 {
    return *(const float2*)(xrow + i00 + it * 4);
  };
  // expand: scatter (w0,w1) into the zeroed 16-slot f16 row of As[(it)&1].
  // slot lo -> u32 word lo>>1 (half lo&1); slot lo+1 is the other half /
  // next word. lo<=11 -> words touched <=6; words 6,7 re-zeroed each iter.
  auto expand = [&](int it, float2 xv) {
    char* Ab = As[it & 1];
#pragma unroll
    for (int d = 0; d < 2; ++d) {
      float w0, w1; int lo;
      kan_weights(d ? xv.y : xv.x, w0, w1, lo);
      const uint32_t wp  = (uint32_t)f16_bits(w0) | ((uint32_t)f16_bits(w1) << 16);
      const uint32_t wlo = (lo & 1) ? (wp << 16) : wp;
      const uint32_t whi = (lo & 1) ? (wp >> 16) : 0u;
      uint32_t* r = (uint32_t*)(Ab + (size_t)((p_ip + d) * 128 + p_row) * 32);
      *(uint4*)(r)     = make_uint4(0u, 0u, 0u, 0u);
      *(uint4*)(r + 4) = make_uint4(0u, 0u, 0u, 0u);
      r[(lo >> 1) + 1] = whi;     // distinct word from wlo; order vs wlo irrelevant
      r[lo >> 1]       = wlo;
    }
  };

  // ---- prologue: x(0) first (so its wait doesn't drain B asyncs), B(0), expand(0) ----
  float2 xc = loadx(0);
  stageB(0);
  expand(0, xc);              // writes As[0]; synced by barrier at it=0
  float2 xn = loadx(1);

  for (int it = 0; it < NIT; ++it) {
    __syncthreads();   // syncs As[it&1] writes + drains B(it) asyncs
                       // (which flew through all of compute(it-1))

    if (it + 1 < NIT) {
      stageB(it + 1);                 // flies during compute(it)
      expand(it + 1, xn);             // xn in flight for a full iter already
      if (it + 2 < NIT) xn = loadx(it + 2);
    }

    // ---- compute(it) ----
    const char* Bd = (const char*)Bs[it & 1];
    const char* Ad = (const char*)As[it & 1];
#pragma unroll
    for (int ks = 0; ks < 2; ++ks) {
      const int iloc = ks * 2 + (fq >> 1);
      f16x8 af[4];
#pragma unroll
      for (int mi = 0; mi < 4; ++mi)
        af[mi] = *(const f16x8*)(Ad +
                   ((iloc * 128 + mw * 64 + mi * 16 + fr) * 32 + (fq & 1) * 16));
#pragma unroll
      for (int ni = 0; ni < 4; ++ni) {
        const int row = nw * 64 + ni * 16 + fr;
        const int col = ks * 4 + fq;
        const f16x8 bf = *(const f16x8*)(Bd + (row * 8 + (col ^ (row & 7))) * 16);
#pragma unroll
        for (int mi = 0; mi < 4; ++mi)
          acc[mi][ni] = __builtin_amdgcn_mfma_f32_16x16x32_f16(af[mi], bf, acc[mi][ni], 0, 0, 0);
      }
    }
  }

#pragma unroll
  for (int mi = 0; mi < 4; ++mi) {
    const int gr = m0 + mw * 64 + mi * 16 + fq * 4;
#pragma unroll
    for (int ni = 0; ni < 4; ++ni) {
      const int gc = n0 + nw * 64 + ni * 16 + fr;
#pragma unroll
      for (int r = 0; r < 4; ++r)
        atomicAdd(&out[(size_t)(gr + r) * GNN + gc], acc[mi][ni][r]);
    }
  }
}

// ================= fallback: direct dot2 path (no workspace) =================
#define TI 8
#define BT 256
#define JT 32
#define ISPL 2
#define IRANGE (1024 / ISPL)

__global__ __launch_bounds__(256)
void kan_dot2(const float* __restrict__ x, const float* __restrict__ coef,
              float* __restrict__ out) {
  __shared__ uint32_t Plds[TI * 12 * JT];
  const int t    = threadIdx.x;
  const int b    = blockIdx.x * BT + t;
  const int j0   = blockIdx.y * JT;
  const int cbeg = blockIdx.z * (IRANGE / TI);

  float acc[JT];
#pragma unroll
  for (int q = 0; q < JT; ++q) acc[q] = 0.0f;

  const int s_jj   = t & 31;
  const int s_iloc = t >> 5;

  for (int c = cbeg; c < cbeg + IRANGE / TI; ++c) {
    const int i0 = c * TI;
    __syncthreads();
    {
      const float* cp0 = coef + ((size_t)(j0 + s_jj) * 1024 + (i0 + s_iloc)) * 13;
      float cv[13];
#pragma unroll
      for (int s = 0; s < 13; ++s) cv[s] = cp0[s];
#pragma unroll
      for (int r = 0; r < 12; ++r) {
        half2_v h; h[0] = (_Float16)cv[r]; h[1] = (_Float16)cv[r + 1];
        const int slot = ((s_jj >> 2) + r) & 7;
        Plds[(s_iloc * 12 + r) * 32 + slot * 4 + (s_jj & 3)] = h2_as_u32(h);
      }
    }
    uint32_t wr[TI]; int lor[TI];
    {
      const float* xr = x + (size_t)b * 1024 + i0;
      const float4 xa = *(const float4*)(xr);
      const float4 xb = *(const float4*)(xr + 4);
      const float xv[TI] = {xa.x, xa.y, xa.z, xa.w, xb.x, xb.y, xb.z, xb.w};
#pragma unroll
      for (int q = 0; q < TI; ++q) {
        float w0, w1; int lo;
        kan_weights(xv[q], w0, w1, lo);
        wr[q] = (uint32_t)f16_bits(w0) | ((uint32_t)f16_bits(w1) << 16);
        lor[q] = lo;
      }
    }
    __syncthreads();

    const uint4* P4 = (const uint4*)Plds;
#pragma unroll
    for (int ii = 0; ii < TI; ++ii) {
      const half2_v hw = u32_as_h2(wr[ii]);
      const int lo = lor[ii];
      const int base = (ii * 12 + lo) * 8;
#pragma unroll
      for (int g = 0; g < 8; ++g) {
        const uint4 v = P4[base + ((g + lo) & 7)];
        acc[4 * g + 0] = dot2f(hw, u32_as_h2(v.x), acc[4 * g + 0]);
        acc[4 * g + 1] = dot2f(hw, u32_as_h2(v.y), acc[4 * g + 1]);
        acc[4 * g + 2] = dot2f(hw, u32_as_h2(v.z), acc[4 * g + 2]);
        acc[4 * g + 3] = dot2f(hw, u32_as_h2(v.w), acc[4 * g + 3]);
      }
    }
  }

  float* orow = out + (size_t)b * 256 + j0;
#pragma unroll
  for (int q = 0; q < JT; ++q) atomicAdd(orow + q, acc[q]);
}

extern "C" void kernel_launch(void* const* d_in, const int* in_sizes, int n_in,
                              void* d_out, int out_size, void* d_ws, size_t ws_size,
                              hipStream_t stream) {
  const float* x     = (const float*)d_in[0];
  const float* coef  = (const float*)d_in[1];
  float* out = (float*)d_out;

  (void)hipMemsetAsync(out, 0, (size_t)out_size * sizeof(float), stream);

  const size_t nB2 = (size_t)GNN * GK2;                  // f16 elements (8.4 MB)
  if (ws_size >= nB2 * 2) {
    _Float16* B2 = (_Float16*)d_ws;
    kan_prep_B2<<<(int)((size_t)GNN * 1024 / 256), 256, 0, stream>>>(coef, (uint32_t*)B2);
    dim3 grid(GMM / BM2, GNN / BN2, KSPL2);              // (64, 2, 4) = 512 blocks
    kan_gemm6<<<grid, 256, 0, stream>>>(x, B2, out);
  } else {
    dim3 grid(8192 / BT, 256 / JT, ISPL);
    kan_dot2<<<grid, 256, 0, stream>>>(x, coef, out);
  }
}

// Round 2
// 194.034 us; speedup vs baseline: 1.1677x; 1.0171x over previous
//
#include <hip/hip_runtime.h>
#include <cstdint>
#include <cstddef>

// KAN layer: out[b,j] = sum_{i,k} basis_k(tanh x[b,i]) * C[j,i,k]
// basis is 2-sparse (adjacent slots lo, lo+1); pad to 16 slots/i.
// R13: 256x256 block (512 thr, 8 waves 2m x 4n, wave tile 128x64), KSPL2=8,
// grid (8,1,32)=256 blocks = 1/CU. vs R12: LDS traffic/unit -34% (panel
// writes + staging amortize over 4 quadrants), expand VALU halved (full-N
// block => each x expanded once), barriers/CU-timeline 128->32. A-panel
// XOR swizzle (half ^= (row>>2)&1) makes zero-writes AND frag reads the
// exact 8-words/bank minimum (R12 had 7.5M conflict cycles: zero-writes hit
// only 4 of 8 bank groups). Grid z-major so i-split -> XCD is 1:1 (B2
// window shared within one L2).

typedef _Float16 half2_v __attribute__((ext_vector_type(2)));
typedef __fp16  fp16x2  __attribute__((ext_vector_type(2)));
typedef _Float16 f16x8 __attribute__((ext_vector_type(8)));
typedef float f32x4 __attribute__((ext_vector_type(4)));

__device__ __forceinline__ half2_v u32_as_h2(uint32_t u) {
  union { uint32_t u; half2_v h; } c; c.u = u; return c.h;
}
__device__ __forceinline__ uint32_t h2_as_u32(half2_v h) {
  union { uint32_t u; half2_v h; } c; c.h = h; return c.u;
}
__device__ __forceinline__ half2_v cvt_pk_h2(float a, float b) {
  union { fp16x2 f; half2_v h; } c;
  c.f = __builtin_amdgcn_cvt_pkrtz(a, b);
  return c.h;
}
__device__ __forceinline__ float dot2f(half2_v a, half2_v b, float c) {
#if __has_builtin(__builtin_amdgcn_fdot2)
  return __builtin_amdgcn_fdot2(a, b, c, false);
#else
  return c + (float)a[0] * (float)b[0] + (float)a[1] * (float)b[1];
#endif
}
__device__ __forceinline__ uint16_t f16_bits(float v) {
  union { _Float16 h; uint16_t u; } c; c.h = (_Float16)v; return c.u;
}

__device__ __forceinline__ float fast_tanhf(float v) {
  const float e = __expf(2.0f * v);
  return 1.0f - 2.0f / (e + 1.0f);
}

// ---- basis-weight computation (analytic uniform knots; verified R10) ----
#define KSTEP 0.13333333333333333f
#define KINV  7.49999943750004f      // 1/(2/15 + 1e-8)
__device__ __forceinline__ void kan_weights(float xin, float& w0, float& w1, int& lo) {
  float xc = fast_tanhf(xin);
  xc = fminf(fmaxf(xc, -1.0f), 1.0f);
  int m = (int)((xc + 1.0f) * 7.5f);   // interval index; basis continuity makes +-1 ULP safe
  m = min(max(m, 0), 14);
  const float k0 = fmaf((float)m, KSTEP, -1.0f);
  const float up = (xc - k0) * KINV;
  const float dn = (k0 + KSTEP - xc) * KINV;
  // m==0: up on slot 0 | 1<=m<=11: dn on m-1, up on m | m==12: dn on 11 | m>=13: zero
  w0 = (m == 0) ? up : ((m <= 12) ? dn : 0.0f);
  w1 = (m >= 1 && m <= 11) ? up : 0.0f;
  lo = min(max(m - 1, 0), 11);
}

__device__ __forceinline__ void load_lds16(const void* g, void* l) {
  __builtin_amdgcn_global_load_lds((const __attribute__((address_space(1))) void*)g,
                                   (__attribute__((address_space(3))) void*)l, 16, 0, 0);
}

// ================= fast path =================
#define GMM 8192
#define GNN 256
#define KI  16                 // padded slots per i
#define GK2 (1024 * KI)        // 16384
#define KSPL2 8
#define IPER (1024 / KSPL2)    // 128 i per split
#define BM2 256
#define BN2 256
#define NIT (IPER / 4)         // 32 pipeline iters (4 i each)

// prep_B2: f16 B2[j][i*16+s], s=0..11 from coef, 12..15 zero (slot12 unused).
__global__ __launch_bounds__(256)
void kan_prep_B2(const float* __restrict__ coef, uint32_t* __restrict__ B2) {
  const int tid = blockIdx.x * 256 + threadIdx.x;   // flat (j,i), 262144
  const float* cp = coef + (size_t)tid * 13;
  uint32_t w[8];
#pragma unroll
  for (int q = 0; q < 6; ++q) w[q] = h2_as_u32(cvt_pk_h2(cp[2 * q], cp[2 * q + 1]));
  w[6] = 0u; w[7] = 0u;
  uint4* p = (uint4*)(B2 + (size_t)tid * 8);
  p[0] = make_uint4(w[0], w[1], w[2], w[3]);
  p[1] = make_uint4(w[4], w[5], w[6], w[7]);
}

__global__ __launch_bounds__(512, 2)
void kan_gemm7(const float* __restrict__ x, const _Float16* __restrict__ B2,
               float* __restrict__ out) {
  // Bs: double-buffered 2x32 KB (XOR-swizzled on the global side since
  // global_load_lds LDS addr = uniform base + lane*16).
  // As: double-buffered 2x32 KB expanded A-panel [4 i][256 rows][16 f16],
  // with 16-B halves swapped when (row>>2)&1 (bank spread).
  __shared__ __align__(16) char Bs[2][BN2 * 128];
  __shared__ __align__(16) char As[2][4 * BM2 * 32];

  const int t    = threadIdx.x;
  const int lane = t & 63;
  const int wv   = t >> 6;          // 0..7
  const int mw   = wv & 1;          // m-half of block (128)
  const int nw   = wv >> 1;         // n-quarter of block (64)
  const int fr   = lane & 15;
  const int fq   = lane >> 4;
  const int m0   = blockIdx.z * BM2;
  const int i00  = blockIdx.x * IPER;
  const int fr_swz = ((fr >> 2) & 1) * 16;   // A-panel half-swap bit for reads
  const int a_half = (fq & 1) * 16;          // logical 16-B half within 16-slot row

  f32x4 acc[8][4];
#pragma unroll
  for (int a = 0; a < 8; ++a)
#pragma unroll
    for (int b = 0; b < 4; ++b) acc[a][b] = (f32x4){0.f, 0.f, 0.f, 0.f};

  // B staging: 2048 16-B chunks (4/thread), XOR swizzle applied on global side.
  const int sn[4] = { (0 * 512 + t) >> 3, (1 * 512 + t) >> 3,
                      (2 * 512 + t) >> 3, (3 * 512 + t) >> 3 };
  const int sc = t & 7;
  // A-panel production: thread t -> row p_row, i-pair {p_ip, p_ip+1}.
  const int p_row = t & 255;
  const int p_ip  = (t >> 8) * 2;   // 0 or 2
  const int p_swz = ((p_row >> 2) & 1) * 16;
  const float* xrow = x + (size_t)(m0 + p_row) * 1024 + p_ip;

  auto stageB = [&](int it) {
    const _Float16* Bb = B2 + (size_t)(i00 + it * 4) * KI;
    char* Bd = (char*)Bs[it & 1];
#pragma unroll
    for (int s = 0; s < 4; ++s) {
      const int c = sc ^ (sn[s] & 7);
      load_lds16(Bb + (size_t)sn[s] * GK2 + c * 8, Bd + (s * 512 + t) * 16);
    }
  };
  auto loadx = [&](int it) -> float2 {
    return *(const float2*)(xrow + i00 + it * 4);
  };
  // expand: zero the 32-B row (halves written in swizzled order so each
  // instruction's 64 lanes cover all 8 bank groups), then scatter (w0,w1).
  auto expand = [&](int it, float2 xv) {
    char* Ab = As[it & 1];
#pragma unroll
    for (int d = 0; d < 2; ++d) {
      float w0, w1; int lo;
      kan_weights(d ? xv.y : xv.x, w0, w1, lo);
      const uint32_t wp  = (uint32_t)f16_bits(w0) | ((uint32_t)f16_bits(w1) << 16);
      const uint32_t wlo = (lo & 1) ? (wp << 16) : wp;
      const uint32_t whi = (lo & 1) ? (wp >> 16) : 0u;
      const int w = lo >> 1;                      // u32 word 0..5
      char* rb = Ab + (size_t)((p_ip + d) * BM2 + p_row) * 32;
      *(uint4*)(rb + p_swz)        = make_uint4(0u, 0u, 0u, 0u);
      *(uint4*)(rb + (p_swz ^ 16)) = make_uint4(0u, 0u, 0u, 0u);
      *(uint32_t*)(rb + (((w + 1) * 4) ^ p_swz)) = whi;  // distinct word from wlo
      *(uint32_t*)(rb + ((w * 4) ^ p_swz))       = wlo;
    }
  };

  // ---- prologue: x(0) first (so its wait doesn't drain B asyncs), B(0), expand(0) ----
  float2 xc = loadx(0);
  stageB(0);
  expand(0, xc);              // writes As[0]; synced by barrier at it=0
  float2 xn = loadx(1);

  for (int it = 0; it < NIT; ++it) {
    __syncthreads();   // syncs As[it&1] writes + drains B(it) asyncs
                       // (which flew through all of compute(it-1))

    if (it + 1 < NIT) {
      stageB(it + 1);                 // flies during compute(it)
      expand(it + 1, xn);             // xn in flight for a full iter already
      if (it + 2 < NIT) xn = loadx(it + 2);
    }

    // ---- compute(it) ----
    const char* Bd = (const char*)Bs[it & 1];
    const char* Ad = (const char*)As[it & 1];
#pragma unroll
    for (int ks = 0; ks < 2; ++ks) {
      const int iloc = ks * 2 + (fq >> 1);
      f16x8 bf[4];
#pragma unroll
      for (int ni = 0; ni < 4; ++ni) {
        const int row = nw * 64 + ni * 16 + fr;
        bf[ni] = *(const f16x8*)(Bd + (row * 8 + ((ks * 4 + fq) ^ (row & 7))) * 16);
      }
#pragma unroll
      for (int mi = 0; mi < 8; ++mi) {
        const f16x8 af = *(const f16x8*)(Ad +
            (size_t)((iloc * BM2 + mw * 128 + mi * 16 + fr) * 32) + (a_half ^ fr_swz));
#pragma unroll
        for (int ni = 0; ni < 4; ++ni)
          acc[mi][ni] = __builtin_amdgcn_mfma_f32_16x16x32_f16(af, bf[ni], acc[mi][ni], 0, 0, 0);
      }
    }
  }

#pragma unroll
  for (int mi = 0; mi < 8; ++mi) {
    const int gr = m0 + mw * 128 + mi * 16 + fq * 4;
#pragma unroll
    for (int ni = 0; ni < 4; ++ni) {
      const int gc = nw * 64 + ni * 16 + fr;
#pragma unroll
      for (int r = 0; r < 4; ++r)
        atomicAdd(&out[(size_t)(gr + r) * GNN + gc], acc[mi][ni][r]);
    }
  }
}

// ================= fallback: direct dot2 path (no workspace) =================
#define TI 8
#define BT 256
#define JT 32
#define ISPL 2
#define IRANGE (1024 / ISPL)

__global__ __launch_bounds__(256)
void kan_dot2(const float* __restrict__ x, const float* __restrict__ coef,
              float* __restrict__ out) {
  __shared__ uint32_t Plds[TI * 12 * JT];
  const int t    = threadIdx.x;
  const int b    = blockIdx.x * BT + t;
  const int j0   = blockIdx.y * JT;
  const int cbeg = blockIdx.z * (IRANGE / TI);

  float acc[JT];
#pragma unroll
  for (int q = 0; q < JT; ++q) acc[q] = 0.0f;

  const int s_jj   = t & 31;
  const int s_iloc = t >> 5;

  for (int c = cbeg; c < cbeg + IRANGE / TI; ++c) {
    const int i0 = c * TI;
    __syncthreads();
    {
      const float* cp0 = coef + ((size_t)(j0 + s_jj) * 1024 + (i0 + s_iloc)) * 13;
      float cv[13];
#pragma unroll
      for (int s = 0; s < 13; ++s) cv[s] = cp0[s];
#pragma unroll
      for (int r = 0; r < 12; ++r) {
        half2_v h; h[0] = (_Float16)cv[r]; h[1] = (_Float16)cv[r + 1];
        const int slot = ((s_jj >> 2) + r) & 7;
        Plds[(s_iloc * 12 + r) * 32 + slot * 4 + (s_jj & 3)] = h2_as_u32(h);
      }
    }
    uint32_t wr[TI]; int lor[TI];
    {
      const float* xr = x + (size_t)b * 1024 + i0;
      const float4 xa = *(const float4*)(xr);
      const float4 xb = *(const float4*)(xr + 4);
      const float xv[TI] = {xa.x, xa.y, xa.z, xa.w, xb.x, xb.y, xb.z, xb.w};
#pragma unroll
      for (int q = 0; q < TI; ++q) {
        float w0, w1; int lo;
        kan_weights(xv[q], w0, w1, lo);
        wr[q] = (uint32_t)f16_bits(w0) | ((uint32_t)f16_bits(w1) << 16);
        lor[q] = lo;
      }
    }
    __syncthreads();

    const uint4* P4 = (const uint4*)Plds;
#pragma unroll
    for (int ii = 0; ii < TI; ++ii) {
      const half2_v hw = u32_as_h2(wr[ii]);
      const int lo = lor[ii];
      const int base = (ii * 12 + lo) * 8;
#pragma unroll
      for (int g = 0; g < 8; ++g) {
        const uint4 v = P4[base + ((g + lo) & 7)];
        acc[4 * g + 0] = dot2f(hw, u32_as_h2(v.x), acc[4 * g + 0]);
        acc[4 * g + 1] = dot2f(hw, u32_as_h2(v.y), acc[4 * g + 1]);
        acc[4 * g + 2] = dot2f(hw, u32_as_h2(v.z), acc[4 * g + 2]);
        acc[4 * g + 3] = dot2f(hw, u32_as_h2(v.w), acc[4 * g + 3]);
      }
    }
  }

  float* orow = out + (size_t)b * 256 + j0;
#pragma unroll
  for (int q = 0; q < JT; ++q) atomicAdd(orow + q, acc[q]);
}

extern "C" void kernel_launch(void* const* d_in, const int* in_sizes, int n_in,
                              void* d_out, int out_size, void* d_ws, size_t ws_size,
                              hipStream_t stream) {
  const float* x     = (const float*)d_in[0];
  const float* coef  = (const float*)d_in[1];
  float* out = (float*)d_out;

  (void)hipMemsetAsync(out, 0, (size_t)out_size * sizeof(float), stream);

  const size_t nB2 = (size_t)GNN * GK2;                  // f16 elements (8.4 MB)
  if (ws_size >= nB2 * 2) {
    _Float16* B2 = (_Float16*)d_ws;
    kan_prep_B2<<<(int)((size_t)GNN * 1024 / 256), 256, 0, stream>>>(coef, (uint32_t*)B2);
    // z-major grid: linear id = x + 8*z -> XCD = i-split id; all 32 blocks
    // sharing a B2 i-window land on one XCD's L2.
    dim3 grid(KSPL2, 1, GMM / BM2);                      // (8, 1, 32) = 256 blocks
    kan_gemm7<<<grid, 512, 0, stream>>>(x, B2, out);
  } else {
    dim3 grid(8192 / BT, 256 / JT, ISPL);
    kan_dot2<<<grid, 256, 0, stream>>>(x, coef, out);
  }
}